// Round 1
// baseline (1766.903 us; speedup 1.0000x reference)
//
#include <hip/hip_runtime.h>

// GeneralizedGraphDiffusion: out = PReLU((sum_k theta_k*T_k * a) @ x) @ W^T + b
// N=8192, D=128, K=4, fp32 throughout.
//
// K1: streams T (1 GiB) + a (256 MiB) once; fused q-formation + q@x row update.
//     j split into 8 segments -> partial h accumulated via fp32 global atomics.
// K_prep: PReLU in place on h; transpose W -> Wt (for coalesced K2 reads).
// K2: out[row][:] = b + sum_d ph[row][d] * Wt[d][:], one wave per row.

#define NN_DIM 8192
#define DF 128
#define NSEG 8
#define RPW 8  // rows per wave in K1

__global__ __launch_bounds__(256, 4)
void k1_diffuse(const float* __restrict__ theta,
                const float* __restrict__ T,   // [4][N][N]
                const float* __restrict__ x,   // [N][128]
                const float* __restrict__ a,   // [N][N]
                float* __restrict__ h)         // [N][128], pre-zeroed, atomic accumulate
{
  const int lane = threadIdx.x & 63;
  const int wv   = threadIdx.x >> 6;
  const int seg  = blockIdx.x & (NSEG - 1);   // which 1024-column j segment
  const int rblk = blockIdx.x >> 3;           // 256 row-blocks of 32 rows
  const int row0 = rblk * 32 + wv * RPW;      // this wave's 8 rows

  const float th0 = theta[0], th1 = theta[1], th2 = theta[2], th3 = theta[3];

  float2 acc[RPW];
#pragma unroll
  for (int r = 0; r < RPW; ++r) acc[r] = make_float2(0.f, 0.f);

  const int d0 = lane * 2;                    // this lane's feature pair
  const int jseg = seg * (NN_DIM / NSEG);     // 1024 columns per segment
  const size_t NN2 = (size_t)NN_DIM * NN_DIM;

  for (int chunk = 0; chunk < (NN_DIM / NSEG) / 128; ++chunk) {  // 8 chunks of 128 cols
    const int j0 = jseg + chunk * 128;
    const int jl = j0 + lane * 2;             // this lane's 2 columns
    float2 q[RPW];
#pragma unroll
    for (int r = 0; r < RPW; ++r) {
      const size_t ro = (size_t)(row0 + r) * NN_DIM + jl;
      const float2 t0 = *(const float2*)(T + ro);
      const float2 t1 = *(const float2*)(T + NN2 + ro);
      const float2 t2 = *(const float2*)(T + 2 * NN2 + ro);
      const float2 t3 = *(const float2*)(T + 3 * NN2 + ro);
      const float2 av = *(const float2*)(a + ro);
      q[r].x = (th0 * t0.x + th1 * t1.x + th2 * t2.x + th3 * t3.x) * av.x;
      q[r].y = (th0 * t0.y + th1 * t1.y + th2 * t2.y + th3 * t3.y) * av.y;
    }
    // inner: broadcast q (lane l holds cols j0+2l, j0+2l+1) against x rows
    const float* xp = x + (size_t)j0 * DF + d0;
#pragma unroll 2
    for (int l = 0; l < 64; ++l) {
      const float2 xv0 = *(const float2*)(xp);
      const float2 xv1 = *(const float2*)(xp + DF);
      xp += 2 * DF;
#pragma unroll
      for (int r = 0; r < RPW; ++r) {
        const float q0 = __int_as_float(
            __builtin_amdgcn_readlane(__float_as_int(q[r].x), l));
        acc[r].x += q0 * xv0.x;
        acc[r].y += q0 * xv0.y;
      }
#pragma unroll
      for (int r = 0; r < RPW; ++r) {
        const float q1 = __int_as_float(
            __builtin_amdgcn_readlane(__float_as_int(q[r].y), l));
        acc[r].x += q1 * xv1.x;
        acc[r].y += q1 * xv1.y;
      }
    }
  }

#pragma unroll
  for (int r = 0; r < RPW; ++r) {
    float* hp = h + (size_t)(row0 + r) * DF + d0;
    atomicAdd(hp, acc[r].x);
    atomicAdd(hp + 1, acc[r].y);
  }
}

// PReLU in place on h; also transpose W (128x128) into Wt for coalesced K2 reads.
__global__ __launch_bounds__(256)
void k_prep(float* __restrict__ h, const float* __restrict__ alpha,
            const float* __restrict__ W, float* __restrict__ Wt)
{
  const int i = blockIdx.x * 256 + threadIdx.x;   // 0 .. N*DF-1
  const float v = h[i];
  const float al = alpha[i & (DF - 1)];
  h[i] = v > 0.f ? v : al * v;
  if (i < DF * DF) {
    // W[do][d] at i (do=i>>7, d=i&127) -> Wt[d][do]
    Wt[(i & (DF - 1)) * DF + (i >> 7)] = W[i];
  }
}

// out[row][do] = b[do] + sum_d ph[row][d] * Wt[d][do]; one wave per row.
__global__ __launch_bounds__(256)
void k2_out(const float* __restrict__ ph, const float* __restrict__ Wt,
            const float* __restrict__ b, float* __restrict__ out)
{
  const int lane = threadIdx.x & 63;
  const int wv   = threadIdx.x >> 6;
  const int row  = blockIdx.x * 4 + wv;
  const int d0   = lane * 2;                  // this lane's output-feature pair

  const float* phr = ph + (size_t)row * DF;
  float2 acc = *(const float2*)(b + d0);
#pragma unroll 4
  for (int d = 0; d < DF; ++d) {
    const float pv = phr[d];                          // wave-uniform -> s_load
    const float2 w2 = *(const float2*)(Wt + d * DF + d0);  // coalesced, L1-hot
    acc.x += pv * w2.x;
    acc.y += pv * w2.y;
  }
  *(float2*)(out + (size_t)row * DF + d0) = acc;
}

extern "C" void kernel_launch(void* const* d_in, const int* in_sizes, int n_in,
                              void* d_out, int out_size, void* d_ws, size_t ws_size,
                              hipStream_t stream) {
  const float* theta = (const float*)d_in[0];
  const float* T     = (const float*)d_in[1];
  const float* x     = (const float*)d_in[2];
  const float* a     = (const float*)d_in[3];
  const float* alpha = (const float*)d_in[4];
  const float* W     = (const float*)d_in[5];
  const float* b     = (const float*)d_in[6];
  float* out = (float*)d_out;

  float* h  = (float*)d_ws;                              // N*128 fp32 = 4 MiB
  float* Wt = (float*)d_ws + (size_t)NN_DIM * DF;        // 128*128 fp32 = 64 KiB

  hipMemsetAsync(h, 0, (size_t)NN_DIM * DF * sizeof(float), stream);

  k1_diffuse<<<NSEG * (NN_DIM / 32), 256, 0, stream>>>(theta, T, x, a, h);
  k_prep<<<(NN_DIM * DF) / 256, 256, 0, stream>>>(h, alpha, W, Wt);
  k2_out<<<NN_DIM / 4, 256, 0, stream>>>(h, Wt, b, out);
}